// Round 12
// baseline (2397.376 us; speedup 1.0000x reference)
//
#include <hip/hip_runtime.h>
#include <math.h>

#define TT 64
#define BB 2048

using f32x4   = __attribute__((ext_vector_type(4))) float;
using short8  = __attribute__((ext_vector_type(8))) short;
using short4v = __attribute__((ext_vector_type(4))) short;

__device__ __forceinline__ unsigned short f2bf(float f) {
    unsigned u = __float_as_uint(f);
    u += 0x7FFF + ((u >> 16) & 1);
    return (unsigned short)(u >> 16);
}
__device__ __forceinline__ float bf2f(unsigned short h) {
    return __uint_as_float(((unsigned)h) << 16);
}
__device__ __forceinline__ float sigmoidf_(float v) { return 1.0f / (1.0f + expf(-v)); }
__device__ __forceinline__ float tanhf_(float v)    { return 1.0f - 2.0f / (expf(2.0f * v) + 1.0f); }

// pack src[N rows][Ksrc cols] sub-block (cols kbeg..kbeg+Kpk) into bf16 MFMA fragment order
__global__ __launch_bounds__(256)
void pack_w2(const float* __restrict__ src, unsigned short* __restrict__ dst,
             int N, int Ksrc, int kbeg, int Kpk) {
    int i = blockIdx.x * 256 + threadIdx.x;
    if (i >= N * Kpk) return;
    int n = i / Kpk, k = i - n * Kpk;
    int dstIdx = ((n >> 4) * (Kpk >> 5) + (k >> 5)) * 512 + (((k >> 3) & 3) * 16 + (n & 15)) * 8 + (k & 7);
    dst[dstIdx] = f2bf(src[(size_t)n * Ksrc + kbeg + k]);
}

// fused packer for the hoist path: 7 segments of 512x512, one launch (7168 blocks x 256)
__global__ __launch_bounds__(256)
void pack_all(const float* __restrict__ Wr, const float* __restrict__ Wz,
              const float* __restrict__ Wc, const float* __restrict__ Wo,
              unsigned short* __restrict__ Wrz_h, unsigned short* __restrict__ Wc_h,
              unsigned short* __restrict__ Wx3, unsigned short* __restrict__ Wo_pk) {
    int i = blockIdx.x * 256 + threadIdx.x;
    int seg = i >> 18;                 // 512*512 = 2^18
    int r = i & 262143;
    int n = r >> 9, k = r & 511;
    int dstIdx = ((n >> 4) * 16 + (k >> 5)) * 512 + (((k >> 3) & 3) * 16 + (n & 15)) * 8 + (k & 7);
    const float* src; unsigned short* dst; int kb, Ksrc;
    switch (seg) {
        case 0: src = Wr; dst = Wrz_h;               kb = 512; Ksrc = 1024; break;
        case 1: src = Wz; dst = Wrz_h + 262144;      kb = 512; Ksrc = 1024; break;
        case 2: src = Wc; dst = Wc_h;                kb = 512; Ksrc = 1024; break;
        case 3: src = Wr; dst = Wx3;                 kb = 0;   Ksrc = 1024; break;
        case 4: src = Wz; dst = Wx3 + 262144;        kb = 0;   Ksrc = 1024; break;
        case 5: src = Wc; dst = Wx3 + 2 * 262144;    kb = 0;   Ksrc = 1024; break;
        default: src = Wo; dst = Wo_pk;              kb = 0;   Ksrc = 512;  break;
    }
    dst[dstIdx] = f2bf(src[(size_t)n * Ksrc + kb + k]);
}

// packed index inside a [16 rows][512 cols] tile (fragment order)
__device__ __forceinline__ int pk_idx(int row, int col) {
    int ks = col >> 5, khi = (col >> 3) & 3, j = col & 7;
    return ((ks * 64) + khi * 16 + row) * 8 + j;
}

// LN one 512-wide row -> packed bf16 tile
__device__ __forceinline__ void ln_row_pk(const float* __restrict__ xr,
                                          const float* __restrict__ g,
                                          const float* __restrict__ b,
                                          unsigned short* __restrict__ tile,
                                          int row, int lane) {
    const int c0 = lane * 8;
    float4 v0 = *(const float4*)(xr + c0);
    float4 v1 = *(const float4*)(xr + c0 + 4);
    float s  = v0.x + v0.y + v0.z + v0.w + v1.x + v1.y + v1.z + v1.w;
    float ss = v0.x*v0.x + v0.y*v0.y + v0.z*v0.z + v0.w*v0.w
             + v1.x*v1.x + v1.y*v1.y + v1.z*v1.z + v1.w*v1.w;
#pragma unroll
    for (int m = 32; m > 0; m >>= 1) { s += __shfl_xor(s, m); ss += __shfl_xor(ss, m); }
    const float mean = s * (1.0f / 512.0f);
    const float var  = ss * (1.0f / 512.0f) - mean * mean;
    const float rs   = rsqrtf(var + 1e-5f);
    float4 g0 = *(const float4*)(g + c0);
    float4 g1 = *(const float4*)(g + c0 + 4);
    float4 b0 = *(const float4*)(b + c0);
    float4 b1 = *(const float4*)(b + c0 + 4);
    short8 o;
    o[0] = (short)f2bf((v0.x - mean) * rs * g0.x + b0.x);
    o[1] = (short)f2bf((v0.y - mean) * rs * g0.y + b0.y);
    o[2] = (short)f2bf((v0.z - mean) * rs * g0.z + b0.z);
    o[3] = (short)f2bf((v0.w - mean) * rs * g0.w + b0.w);
    o[4] = (short)f2bf((v1.x - mean) * rs * g1.x + b1.x);
    o[5] = (short)f2bf((v1.y - mean) * rs * g1.y + b1.y);
    o[6] = (short)f2bf((v1.z - mean) * rs * g1.z + b1.z);
    o[7] = (short)f2bf((v1.w - mean) * rs * g1.w + b1.w);
    *(short8*)&tile[(((lane >> 2) * 64) + (lane & 3) * 16 + row) * 8] = o;
}

// ---------------- precompute gx = LN(seq) @ [Wr_x|Wz_x|Wc_x]^T, fragment-packed bf16 ----------------
__global__ __launch_bounds__(512)
void gx_kernel(const float* __restrict__ seq, const float* __restrict__ gxw,
               const float* __restrict__ bxw, const unsigned short* __restrict__ Wx3,
               unsigned short* __restrict__ gx)
{
    __shared__ unsigned short xt[4 * 8192];
    const int tid  = threadIdx.x;
    const int w    = tid >> 6;
    const int lane = tid & 63;
    const size_t m0 = (size_t)blockIdx.x * 64;
    const int t    = (int)(m0 >> 11);
    const int bloc = (int)((m0 & 2047) >> 4);

#pragma unroll
    for (int rr = 0; rr < 8; ++rr) {
        const int r = w * 8 + rr;
        ln_row_pk(seq + (m0 + r) * 512, gxw, bxw, xt + (r >> 4) * 8192, r & 15, lane);
    }
    __syncthreads();

    for (int nt = 0; nt < 3; ++nt) {
        f32x4 acc[4][4] = {};
#pragma unroll 4
        for (int ks = 0; ks < 16; ++ks) {
            short8 a[4], b[4];
#pragma unroll
            for (int mf = 0; mf < 4; ++mf)
                a[mf] = *(const short8*)&xt[mf * 8192 + (ks * 64 + lane) * 8];
#pragma unroll
            for (int nf = 0; nf < 4; ++nf)
                b[nf] = *(const short8*)(Wx3 + (size_t)(nt * 32 + w * 4 + nf) * 8192 + ks * 512 + lane * 8);
#pragma unroll
            for (int mf = 0; mf < 4; ++mf)
#pragma unroll
                for (int nf = 0; nf < 4; ++nf)
                    acc[mf][nf] = __builtin_amdgcn_mfma_f32_16x16x32_bf16(a[mf], b[nf], acc[mf][nf], 0, 0, 0);
        }
#pragma unroll
        for (int mf = 0; mf < 4; ++mf)
#pragma unroll
            for (int nf = 0; nf < 4; ++nf) {
                const size_t base = (((size_t)t * 128 + bloc + mf) * 96 + nt * 32 + w * 4 + nf) * 256 + lane * 4;
                short4v o;
                o[0] = (short)f2bf(acc[mf][nf][0]);
                o[1] = (short)f2bf(acc[mf][nf][1]);
                o[2] = (short)f2bf(acc[mf][nf][2]);
                o[3] = (short)f2bf(acc[mf][nf][3]);
                *(short4v*)&gx[base] = o;
            }
    }
}

// ---------------- block-local persistent recurrence (round-10 schedule + hn mirror tile) ----------------
// 128 blocks x 512 threads (8 waves); block owns 16 batch rows. No grid sync.
// HOIST=1: x-contributions come from gx (K=512 h-part weights only).
// hn2_s[16][520] (padded row-major) mirrors hn_s for the scalar epilogue reads (2-way banks ~ free).
template<int SBF, int HOIST>
__global__ __launch_bounds__(512)
void recurrent_kernel(const float* __restrict__ seq, const float* __restrict__ ts,
                      const unsigned short* __restrict__ Wrz, const unsigned short* __restrict__ Wc,
                      const float* __restrict__ br, const float* __restrict__ bz,
                      const float* __restrict__ bc,
                      const float* __restrict__ gxw, const float* __restrict__ bxw,
                      const float* __restrict__ gh, const float* __restrict__ bh,
                      const float* __restrict__ gc, const float* __restrict__ bcl,
                      const unsigned short* __restrict__ gx,
                      float* __restrict__ states_f32, unsigned short* __restrict__ states_pk)
{
    __shared__ unsigned short hn_s[16 * 512];
    __shared__ unsigned short rh_s[16 * 512];
    __shared__ unsigned short hn2_s[16 * 520];
    __shared__ unsigned short xn_s[HOIST ? 64 : 16 * 512];
    __shared__ float red_s[16][9];
    __shared__ float red_q[16][9];

    const int tid  = threadIdx.x;
    const int w    = tid >> 6;
    const int lane = tid & 63;
    const int lhi  = lane >> 4;
    const int llo  = lane & 15;
    const int m0   = blockIdx.x * 16;

    for (int i = tid; i < 1024; i += 512) *(short8*)&hn_s[i * 8] = short8{};
    for (int i = tid; i < 16 * 520; i += 512) hn2_s[i] = 0;
    if (!HOIST) {
#pragma unroll
        for (int rr = 0; rr < 2; ++rr) {
            const int r = w * 2 + rr;
            ln_row_pk(seq + (size_t)(m0 + r) * 512, gxw, bxw, xn_s, r, lane);
        }
    }
    __syncthreads();

    for (int t = 0; t < TT; ++t) {
        const unsigned short* gxt = HOIST ? gx + (((size_t)t * 128 + blockIdx.x) * 96) * 256 + lane * 4 : nullptr;

        // ---------- rz GEMM ----------
        {
            f32x4 aR[4], aZ[4];
            if (HOIST) {
#pragma unroll
                for (int f = 0; f < 4; ++f) {
                    short4v g1 = *(const short4v*)(gxt + (size_t)(w * 4 + f) * 256);
                    short4v g2 = *(const short4v*)(gxt + (size_t)(32 + w * 4 + f) * 256);
#pragma unroll
                    for (int i = 0; i < 4; ++i) {
                        aR[f][i] = bf2f((unsigned short)g1[i]);
                        aZ[f][i] = bf2f((unsigned short)g2[i]);
                    }
                }
#pragma unroll 4
                for (int ks = 0; ks < 16; ++ks) {
                    short8 a = *(const short8*)&hn_s[(ks * 64 + lane) * 8];
                    const int off = ks * 512 + lane * 8;
#pragma unroll
                    for (int f = 0; f < 4; ++f) {
                        short8 b1 = *(const short8*)(Wrz + (size_t)(w * 4 + f) * 8192 + off);
                        aR[f] = __builtin_amdgcn_mfma_f32_16x16x32_bf16(a, b1, aR[f], 0, 0, 0);
                        short8 b2 = *(const short8*)(Wrz + (size_t)(32 + w * 4 + f) * 8192 + off);
                        aZ[f] = __builtin_amdgcn_mfma_f32_16x16x32_bf16(a, b2, aZ[f], 0, 0, 0);
                    }
                }
            } else {
#pragma unroll
                for (int f = 0; f < 4; ++f) { aR[f] = f32x4{}; aZ[f] = f32x4{}; }
#pragma unroll 2
                for (int ks = 0; ks < 32; ++ks) {
                    short8 a = (ks < 16) ? *(const short8*)&xn_s[(ks * 64 + lane) * 8]
                                         : *(const short8*)&hn_s[((ks - 16) * 64 + lane) * 8];
                    const int off = ks * 512 + lane * 8;
#pragma unroll
                    for (int f = 0; f < 4; ++f) {
                        short8 b1 = *(const short8*)(Wrz + (size_t)(w * 4 + f) * 16384 + off);
                        aR[f] = __builtin_amdgcn_mfma_f32_16x16x32_bf16(a, b1, aR[f], 0, 0, 0);
                        short8 b2 = *(const short8*)(Wrz + (size_t)(32 + w * 4 + f) * 16384 + off);
                        aZ[f] = __builtin_amdgcn_mfma_f32_16x16x32_bf16(a, b2, aZ[f], 0, 0, 0);
                    }
                }
            }
            // epilogue: r*hn -> rh_s (hn read from padded mirror), z -> regs (reuse aR)
#pragma unroll
            for (int f = 0; f < 4; ++f)
#pragma unroll
                for (int i = 0; i < 4; ++i) {
                    const int row = lhi * 4 + i;
                    const int col = w * 64 + f * 16 + llo;
                    const float rr = sigmoidf_(aR[f][i] + br[col]);
                    const float hv = bf2f(hn2_s[row * 520 + col]);
                    rh_s[pk_idx(row, col)] = f2bf(rr * hv);
                    aR[f][i] = sigmoidf_(aZ[f][i] + bz[col]);
                }
            __syncthreads();   // bar1: rh ready

            // ---------- c GEMM ----------
            f32x4 aC[4];
            if (HOIST) {
#pragma unroll
                for (int f = 0; f < 4; ++f) {
                    short4v g3 = *(const short4v*)(gxt + (size_t)(64 + w * 4 + f) * 256);
#pragma unroll
                    for (int i = 0; i < 4; ++i) aC[f][i] = bf2f((unsigned short)g3[i]);
                }
#pragma unroll 4
                for (int ks = 0; ks < 16; ++ks) {
                    short8 a = *(const short8*)&rh_s[(ks * 64 + lane) * 8];
                    const int off = ks * 512 + lane * 8;
#pragma unroll
                    for (int f = 0; f < 4; ++f) {
                        short8 b1 = *(const short8*)(Wc + (size_t)(w * 4 + f) * 8192 + off);
                        aC[f] = __builtin_amdgcn_mfma_f32_16x16x32_bf16(a, b1, aC[f], 0, 0, 0);
                    }
                }
            } else {
#pragma unroll
                for (int f = 0; f < 4; ++f) aC[f] = f32x4{};
#pragma unroll 2
                for (int ks = 0; ks < 32; ++ks) {
                    short8 a = (ks < 16) ? *(const short8*)&xn_s[(ks * 64 + lane) * 8]
                                         : *(const short8*)&rh_s[((ks - 16) * 64 + lane) * 8];
                    const int off = ks * 512 + lane * 8;
#pragma unroll
                    for (int f = 0; f < 4; ++f) {
                        short8 b1 = *(const short8*)(Wc + (size_t)(w * 4 + f) * 16384 + off);
                        aC[f] = __builtin_amdgcn_mfma_f32_16x16x32_bf16(a, b1, aC[f], 0, 0, 0);
                    }
                }
            }
            __syncthreads();   // bar2: all LDS reads done

            // ---------- epilogue: blend, LN1 -> states, LN2*exp(-dt) -> hn ----------
            float hnew[4][4];
#pragma unroll
            for (int f = 0; f < 4; ++f)
#pragma unroll
                for (int i = 0; i < 4; ++i) {
                    const int row = lhi * 4 + i;
                    const int col = w * 64 + f * 16 + llo;
                    const float htil = tanhf_(aC[f][i] + bc[col]);
                    const float hv = bf2f(hn2_s[row * 520 + col]);
                    const float z = aR[f][i];
                    hnew[f][i] = (1.0f - z) * hv + z * htil;
                }
#pragma unroll
            for (int i = 0; i < 4; ++i) {
                float s = hnew[0][i] + hnew[1][i] + hnew[2][i] + hnew[3][i];
                float q = hnew[0][i]*hnew[0][i] + hnew[1][i]*hnew[1][i]
                        + hnew[2][i]*hnew[2][i] + hnew[3][i]*hnew[3][i];
#pragma unroll
                for (int m = 8; m >= 1; m >>= 1) { s += __shfl_xor(s, m); q += __shfl_xor(q, m); }
                if (llo == 0) { red_s[lhi * 4 + i][w] = s; red_q[lhi * 4 + i][w] = q; }
            }
            __syncthreads();
            float mu[4], rsd[4];
#pragma unroll
            for (int i = 0; i < 4; ++i) {
                float s = 0.f, q = 0.f;
#pragma unroll
                for (int w2 = 0; w2 < 8; ++w2) { s += red_s[lhi * 4 + i][w2]; q += red_q[lhi * 4 + i][w2]; }
                const float m_ = s * (1.0f / 512.0f);
                mu[i]  = m_;
                rsd[i] = rsqrtf(q * (1.0f / 512.0f) - m_ * m_ + 1e-5f);
            }
#pragma unroll
            for (int f = 0; f < 4; ++f)
#pragma unroll
                for (int i = 0; i < 4; ++i) {
                    const int row = lhi * 4 + i;
                    const int col = w * 64 + f * 16 + llo;
                    const float h = (hnew[f][i] - mu[i]) * rsd[i] * gc[col] + bcl[col];
                    if (SBF) states_pk[((size_t)t * 128 + blockIdx.x) * 8192 + pk_idx(row, col)] = f2bf(h);
                    else     states_f32[(size_t)t * BB * 512 + (size_t)(m0 + row) * 512 + col] = h;
                    hnew[f][i] = h;
                }
            if (t + 1 < TT) {
                __syncthreads();
#pragma unroll
                for (int i = 0; i < 4; ++i) {
                    float s = hnew[0][i] + hnew[1][i] + hnew[2][i] + hnew[3][i];
                    float q = hnew[0][i]*hnew[0][i] + hnew[1][i]*hnew[1][i]
                            + hnew[2][i]*hnew[2][i] + hnew[3][i]*hnew[3][i];
#pragma unroll
                    for (int m = 8; m >= 1; m >>= 1) { s += __shfl_xor(s, m); q += __shfl_xor(q, m); }
                    if (llo == 0) { red_s[lhi * 4 + i][w] = s; red_q[lhi * 4 + i][w] = q; }
                }
                __syncthreads();
                float dec_[4];
#pragma unroll
                for (int i = 0; i < 4; ++i) {
                    float s = 0.f, q = 0.f;
#pragma unroll
                    for (int w2 = 0; w2 < 8; ++w2) { s += red_s[lhi * 4 + i][w2]; q += red_q[lhi * 4 + i][w2]; }
                    const float m_ = s * (1.0f / 512.0f);
                    mu[i]  = m_;
                    rsd[i] = rsqrtf(q * (1.0f / 512.0f) - m_ * m_ + 1e-5f);
                    const int grow = m0 + lhi * 4 + i;
                    float dtv = ts[(size_t)grow * TT + t + 1] - ts[(size_t)grow * TT + t];
                    dtv = fminf(fmaxf(dtv, 0.0f), 10.0f);
                    dec_[i] = expf(-dtv);
                }
#pragma unroll
                for (int f = 0; f < 4; ++f)
#pragma unroll
                    for (int i = 0; i < 4; ++i) {
                        const int row = lhi * 4 + i;
                        const int col = w * 64 + f * 16 + llo;
                        const float hv = ((hnew[f][i] - mu[i]) * rsd[i] * gh[col] + bh[col]) * dec_[i];
                        hn_s[pk_idx(row, col)] = f2bf(hv);
                        hn2_s[row * 520 + col] = f2bf(hv);
                    }
                if (!HOIST) {
#pragma unroll
                    for (int rr = 0; rr < 2; ++rr) {
                        const int r = w * 2 + rr;
                        ln_row_pk(seq + ((size_t)(t + 1) * BB + m0 + r) * 512, gxw, bxw, xn_s, r, lane);
                    }
                }
            }
        }
        __syncthreads();
    }
}

// ---------------- final projection + residual + LN ----------------
template<int BF>
__global__ __launch_bounds__(512)
void proj_kernel(const float* __restrict__ S, const unsigned short* __restrict__ Spk,
                 const unsigned short* __restrict__ Wo, const float* __restrict__ bo,
                 const float* __restrict__ seq, const float* __restrict__ gf,
                 const float* __restrict__ bff, float* __restrict__ out)
{
    const int tid  = threadIdx.x;
    const int wave = tid >> 6;
    const int lane = tid & 63;
    const int lhi  = lane >> 4;
    const int llo  = lane & 15;
    const long m0  = (long)blockIdx.x * 64;
    const int t    = (int)(m0 >> 11);
    const int blk  = (int)((m0 & 2047) >> 4);

    f32x4 acc[4][4] = {};
#pragma unroll 2
    for (int ks = 0; ks < 16; ++ks) {
        short8 a[4], b[4];
#pragma unroll
        for (int mf = 0; mf < 4; ++mf) {
            if (BF) {
                a[mf] = *(const short8*)(Spk + ((size_t)t * 128 + blk + mf) * 8192 + (ks * 64 + lane) * 8);
            } else {
                const float* ap = S + (size_t)(m0 + mf * 16 + llo) * 512 + ks * 32 + lhi * 8;
                float4 f0 = *(const float4*)ap;
                float4 f1 = *(const float4*)(ap + 4);
                short8 av;
                av[0] = (short)f2bf(f0.x); av[1] = (short)f2bf(f0.y);
                av[2] = (short)f2bf(f0.z); av[3] = (short)f2bf(f0.w);
                av[4] = (short)f2bf(f1.x); av[5] = (short)f2bf(f1.y);
                av[6] = (short)f2bf(f1.z); av[7] = (short)f2bf(f1.w);
                a[mf] = av;
            }
        }
#pragma unroll
        for (int nf = 0; nf < 4; ++nf)
            b[nf] = *(const short8*)(Wo + (size_t)(wave * 4 + nf) * 8192 + ks * 512 + lane * 8);
#pragma unroll
        for (int mf = 0; mf < 4; ++mf)
#pragma unroll
            for (int nf = 0; nf < 4; ++nf)
                acc[mf][nf] = __builtin_amdgcn_mfma_f32_16x16x32_bf16(a[mf], b[nf], acc[mf][nf], 0, 0, 0);
    }

    __shared__ float red_s[64][9];
    __shared__ float red_q[64][9];

#pragma unroll
    for (int mf = 0; mf < 4; ++mf)
#pragma unroll
        for (int i = 0; i < 4; ++i) {
            const long row = m0 + mf * 16 + lhi * 4 + i;
#pragma unroll
            for (int nf = 0; nf < 4; ++nf) {
                const int col = wave * 64 + nf * 16 + llo;
                acc[mf][nf][i] += bo[col] + seq[(size_t)row * 512 + col];
            }
        }
    float mu[4][4], rstd[4][4];
#pragma unroll
    for (int mf = 0; mf < 4; ++mf)
#pragma unroll
        for (int i = 0; i < 4; ++i) {
            float s = 0.f, q = 0.f;
#pragma unroll
            for (int nf = 0; nf < 4; ++nf) { const float v = acc[mf][nf][i]; s += v; q += v * v; }
#pragma unroll
            for (int m = 8; m >= 1; m >>= 1) { s += __shfl_xor(s, m); q += __shfl_xor(q, m); }
            if (llo == 0) { red_s[mf * 16 + lhi * 4 + i][wave] = s; red_q[mf * 16 + lhi * 4 + i][wave] = q; }
        }
    __syncthreads();
#pragma unroll
    for (int mf = 0; mf < 4; ++mf)
#pragma unroll
        for (int i = 0; i < 4; ++i) {
            const int rl = mf * 16 + lhi * 4 + i;
            float s = 0.f, q = 0.f;
#pragma unroll
            for (int w2 = 0; w2 < 8; ++w2) { s += red_s[rl][w2]; q += red_q[rl][w2]; }
            const float m_ = s * (1.0f / 512.0f);
            mu[mf][i] = m_;
            rstd[mf][i] = rsqrtf(q * (1.0f / 512.0f) - m_ * m_ + 1e-5f);
        }
#pragma unroll
    for (int mf = 0; mf < 4; ++mf)
#pragma unroll
        for (int i = 0; i < 4; ++i) {
            const long row = m0 + mf * 16 + lhi * 4 + i;
#pragma unroll
            for (int nf = 0; nf < 4; ++nf) {
                const int col = wave * 64 + nf * 16 + llo;
                out[(size_t)row * 512 + col] = (acc[mf][nf][i] - mu[mf][i]) * rstd[mf][i] * gf[col] + bff[col];
            }
        }
}

extern "C" void kernel_launch(void* const* d_in, const int* in_sizes, int n_in,
                              void* d_out, int out_size, void* d_ws, size_t ws_size,
                              hipStream_t stream) {
    const float* seq = (const float*)d_in[0];
    const float* ts  = (const float*)d_in[1];
    const float* Wr  = (const float*)d_in[2];
    const float* br  = (const float*)d_in[3];
    const float* Wz  = (const float*)d_in[4];
    const float* bz  = (const float*)d_in[5];
    const float* Wc  = (const float*)d_in[6];
    const float* bc  = (const float*)d_in[7];
    const float* Wo  = (const float*)d_in[8];
    const float* bo  = (const float*)d_in[9];
    const float* gx  = (const float*)d_in[10];
    const float* bx  = (const float*)d_in[11];
    const float* gh  = (const float*)d_in[12];
    const float* bh  = (const float*)d_in[13];
    const float* gc  = (const float*)d_in[14];
    const float* bcl = (const float*)d_in[15];
    const float* gf  = (const float*)d_in[16];
    const float* bf  = (const float*)d_in[17];
    float* out = (float*)d_out;

    char* w0 = (char*)d_ws;
    char* w = w0;
    unsigned short* Wrz_full = (unsigned short*)w; w += (size_t)1024 * 1024 * 2;
    unsigned short* Wc_full  = (unsigned short*)w; w += (size_t)512 * 1024 * 2;
    unsigned short* Wrz_h    = (unsigned short*)w; w += (size_t)1024 * 512 * 2;
    unsigned short* Wc_h     = (unsigned short*)w; w += (size_t)512 * 512 * 2;
    unsigned short* Wx3      = (unsigned short*)w; w += (size_t)1536 * 512 * 2;
    unsigned short* Wo_pk    = (unsigned short*)w; w += (size_t)512 * 512 * 2;

    const size_t GXB = (size_t)TT * 128 * 96 * 256 * 2;      // 402,653,184
    const size_t SBB = (size_t)TT * 128 * 8192 * 2;          // 134,217,728

    const bool hoist = ws_size >= (size_t)(w - w0) + GXB;
    unsigned short* gxbuf = (unsigned short*)w;
    if (hoist) w += GXB;
    const bool sbf = ws_size >= (size_t)(w - w0) + SBB;
    unsigned short* states_pk = (unsigned short*)w;

    if (hoist) {
        pack_all<<<7168, 256, 0, stream>>>(Wr, Wz, Wc, Wo, Wrz_h, Wc_h, Wx3, Wo_pk);
    } else {
        pack_w2<<<2048, 256, 0, stream>>>(Wr, Wrz_full, 512, 1024, 0, 1024);
        pack_w2<<<2048, 256, 0, stream>>>(Wz, Wrz_full + (size_t)512 * 1024, 512, 1024, 0, 1024);
        pack_w2<<<2048, 256, 0, stream>>>(Wc, Wc_full, 512, 1024, 0, 1024);
        pack_w2<<<1024, 256, 0, stream>>>(Wo, Wo_pk, 512, 512, 0, 512);
    }

    if (hoist)
        gx_kernel<<<2048, 512, 0, stream>>>(seq, gx, bx, Wx3, gxbuf);

    const unsigned short* Wa = hoist ? Wrz_h : Wrz_full;
    const unsigned short* Wb = hoist ? Wc_h  : Wc_full;
    if (hoist) {
        if (sbf) recurrent_kernel<1,1><<<128, 512, 0, stream>>>(seq, ts, Wa, Wb, br, bz, bc, gx, bx, gh, bh, gc, bcl, gxbuf, out, states_pk);
        else     recurrent_kernel<0,1><<<128, 512, 0, stream>>>(seq, ts, Wa, Wb, br, bz, bc, gx, bx, gh, bh, gc, bcl, gxbuf, out, states_pk);
    } else {
        if (sbf) recurrent_kernel<1,0><<<128, 512, 0, stream>>>(seq, ts, Wa, Wb, br, bz, bc, gx, bx, gh, bh, gc, bcl, gxbuf, out, states_pk);
        else     recurrent_kernel<0,0><<<128, 512, 0, stream>>>(seq, ts, Wa, Wb, br, bz, bc, gx, bx, gh, bh, gc, bcl, gxbuf, out, states_pk);
    }

    if (sbf)
        proj_kernel<1><<<2048, 512, 0, stream>>>(nullptr, states_pk, Wo_pk, bo, seq, gf, bf, out);
    else
        proj_kernel<0><<<2048, 512, 0, stream>>>(out, nullptr, Wo_pk, bo, seq, gf, bf, out);
}

// Round 13
// 1777.462 us; speedup vs baseline: 1.3488x; 1.3488x over previous
//
#include <hip/hip_runtime.h>
#include <math.h>

#define TT 64
#define BB 2048

using f32x4   = __attribute__((ext_vector_type(4))) float;
using short8  = __attribute__((ext_vector_type(8))) short;
using short4v = __attribute__((ext_vector_type(4))) short;

__device__ __forceinline__ unsigned short f2bf(float f) {
    unsigned u = __float_as_uint(f);
    u += 0x7FFF + ((u >> 16) & 1);
    return (unsigned short)(u >> 16);
}
__device__ __forceinline__ float bf2f(unsigned short h) {
    return __uint_as_float(((unsigned)h) << 16);
}
__device__ __forceinline__ float sigmoidf_(float v) { return 1.0f / (1.0f + expf(-v)); }
__device__ __forceinline__ float tanhf_(float v)    { return 1.0f - 2.0f / (expf(2.0f * v) + 1.0f); }

// pack src[N rows][Ksrc cols] sub-block (cols kbeg..kbeg+Kpk) into MFMA fragment order
__global__ __launch_bounds__(256)
void pack_w2(const float* __restrict__ src, unsigned short* __restrict__ dst,
             int N, int Ksrc, int kbeg, int Kpk) {
    int i = blockIdx.x * 256 + threadIdx.x;
    if (i >= N * Kpk) return;
    int n = i / Kpk, k = i - n * Kpk;
    int dstIdx = ((n >> 4) * (Kpk >> 5) + (k >> 5)) * 512 + (((k >> 3) & 3) * 16 + (n & 15)) * 8 + (k & 7);
    dst[dstIdx] = f2bf(src[(size_t)n * Ksrc + kbeg + k]);
}

// fused packer for the hoist path: 7 segments of 512x512, one launch (7168 blocks x 256)
__global__ __launch_bounds__(256)
void pack_all(const float* __restrict__ Wr, const float* __restrict__ Wz,
              const float* __restrict__ Wc, const float* __restrict__ Wo,
              unsigned short* __restrict__ Wrz_h, unsigned short* __restrict__ Wc_h,
              unsigned short* __restrict__ Wx3, unsigned short* __restrict__ Wo_pk) {
    int i = blockIdx.x * 256 + threadIdx.x;
    int seg = i >> 18;                 // 512*512 = 2^18
    int r = i & 262143;
    int n = r >> 9, k = r & 511;
    int dstIdx = ((n >> 4) * 16 + (k >> 5)) * 512 + (((k >> 3) & 3) * 16 + (n & 15)) * 8 + (k & 7);
    const float* src; unsigned short* dst; int kb, Ksrc;
    switch (seg) {
        case 0: src = Wr; dst = Wrz_h;               kb = 512; Ksrc = 1024; break;
        case 1: src = Wz; dst = Wrz_h + 262144;      kb = 512; Ksrc = 1024; break;
        case 2: src = Wc; dst = Wc_h;                kb = 512; Ksrc = 1024; break;
        case 3: src = Wr; dst = Wx3;                 kb = 0;   Ksrc = 1024; break;
        case 4: src = Wz; dst = Wx3 + 262144;        kb = 0;   Ksrc = 1024; break;
        case 5: src = Wc; dst = Wx3 + 2 * 262144;    kb = 0;   Ksrc = 1024; break;
        default: src = Wo; dst = Wo_pk;              kb = 0;   Ksrc = 512;  break;
    }
    dst[dstIdx] = f2bf(src[(size_t)n * Ksrc + kb + k]);
}

// packed index inside a [16 rows][512 cols] tile (fragment order)
__device__ __forceinline__ int pk_idx(int row, int col) {
    int ks = col >> 5, khi = (col >> 3) & 3, j = col & 7;
    return ((ks * 64) + khi * 16 + row) * 8 + j;
}

// LN one 512-wide row -> packed bf16 tile
__device__ __forceinline__ void ln_row_pk(const float* __restrict__ xr,
                                          const float* __restrict__ g,
                                          const float* __restrict__ b,
                                          unsigned short* __restrict__ tile,
                                          int row, int lane) {
    const int c0 = lane * 8;
    float4 v0 = *(const float4*)(xr + c0);
    float4 v1 = *(const float4*)(xr + c0 + 4);
    float s  = v0.x + v0.y + v0.z + v0.w + v1.x + v1.y + v1.z + v1.w;
    float ss = v0.x*v0.x + v0.y*v0.y + v0.z*v0.z + v0.w*v0.w
             + v1.x*v1.x + v1.y*v1.y + v1.z*v1.z + v1.w*v1.w;
#pragma unroll
    for (int m = 32; m > 0; m >>= 1) { s += __shfl_xor(s, m); ss += __shfl_xor(ss, m); }
    const float mean = s * (1.0f / 512.0f);
    const float var  = ss * (1.0f / 512.0f) - mean * mean;
    const float rs   = rsqrtf(var + 1e-5f);
    float4 g0 = *(const float4*)(g + c0);
    float4 g1 = *(const float4*)(g + c0 + 4);
    float4 b0 = *(const float4*)(b + c0);
    float4 b1 = *(const float4*)(b + c0 + 4);
    short8 o;
    o[0] = (short)f2bf((v0.x - mean) * rs * g0.x + b0.x);
    o[1] = (short)f2bf((v0.y - mean) * rs * g0.y + b0.y);
    o[2] = (short)f2bf((v0.z - mean) * rs * g0.z + b0.z);
    o[3] = (short)f2bf((v0.w - mean) * rs * g0.w + b0.w);
    o[4] = (short)f2bf((v1.x - mean) * rs * g1.x + b1.x);
    o[5] = (short)f2bf((v1.y - mean) * rs * g1.y + b1.y);
    o[6] = (short)f2bf((v1.z - mean) * rs * g1.z + b1.z);
    o[7] = (short)f2bf((v1.w - mean) * rs * g1.w + b1.w);
    *(short8*)&tile[(((lane >> 2) * 64) + (lane & 3) * 16 + row) * 8] = o;
}

// ---------------- precompute gx = LN(seq) @ [Wr_x|Wz_x|Wc_x]^T, fragment-packed bf16 ----------------
__global__ __launch_bounds__(512)
void gx_kernel(const float* __restrict__ seq, const float* __restrict__ gxw,
               const float* __restrict__ bxw, const unsigned short* __restrict__ Wx3,
               unsigned short* __restrict__ gx)
{
    __shared__ unsigned short xt[4 * 8192];
    const int tid  = threadIdx.x;
    const int w    = tid >> 6;
    const int lane = tid & 63;
    const size_t m0 = (size_t)blockIdx.x * 64;
    const int t    = (int)(m0 >> 11);
    const int bloc = (int)((m0 & 2047) >> 4);

#pragma unroll
    for (int rr = 0; rr < 8; ++rr) {
        const int r = w * 8 + rr;
        ln_row_pk(seq + (m0 + r) * 512, gxw, bxw, xt + (r >> 4) * 8192, r & 15, lane);
    }
    __syncthreads();

    for (int nt = 0; nt < 3; ++nt) {
        f32x4 acc[4][4] = {};
#pragma unroll 4
        for (int ks = 0; ks < 16; ++ks) {
            short8 a[4], b[4];
#pragma unroll
            for (int mf = 0; mf < 4; ++mf)
                a[mf] = *(const short8*)&xt[mf * 8192 + (ks * 64 + lane) * 8];
#pragma unroll
            for (int nf = 0; nf < 4; ++nf)
                b[nf] = *(const short8*)(Wx3 + (size_t)(nt * 32 + w * 4 + nf) * 8192 + ks * 512 + lane * 8);
#pragma unroll
            for (int mf = 0; mf < 4; ++mf)
#pragma unroll
                for (int nf = 0; nf < 4; ++nf)
                    acc[mf][nf] = __builtin_amdgcn_mfma_f32_16x16x32_bf16(a[mf], b[nf], acc[mf][nf], 0, 0, 0);
        }
#pragma unroll
        for (int mf = 0; mf < 4; ++mf)
#pragma unroll
            for (int nf = 0; nf < 4; ++nf) {
                const size_t base = (((size_t)t * 128 + bloc + mf) * 96 + nt * 32 + w * 4 + nf) * 256 + lane * 4;
                short4v o;
                o[0] = (short)f2bf(acc[mf][nf][0]);
                o[1] = (short)f2bf(acc[mf][nf][1]);
                o[2] = (short)f2bf(acc[mf][nf][2]);
                o[3] = (short)f2bf(acc[mf][nf][3]);
                *(short4v*)&gx[base] = o;
            }
    }
}

// ---------------- block-local persistent recurrence (round-4 structure, measured 1390us) ----------------
// 128 blocks x 512 threads (8 waves); block owns 16 batch rows. No grid sync.
// HOIST=1: x-contributions come from gx (K=512 h-part weights only).
template<int SBF, int HOIST>
__global__ __launch_bounds__(512)
void recurrent_kernel(const float* __restrict__ seq, const float* __restrict__ ts,
                      const unsigned short* __restrict__ Wrz, const unsigned short* __restrict__ Wc,
                      const float* __restrict__ br, const float* __restrict__ bz,
                      const float* __restrict__ bc,
                      const float* __restrict__ gxw, const float* __restrict__ bxw,
                      const float* __restrict__ gh, const float* __restrict__ bh,
                      const float* __restrict__ gc, const float* __restrict__ bcl,
                      const unsigned short* __restrict__ gx,
                      float* __restrict__ states_f32, unsigned short* __restrict__ states_pk)
{
    __shared__ unsigned short hn_s[16 * 512];
    __shared__ unsigned short rh_s[16 * 512];
    __shared__ unsigned short xn_s[HOIST ? 64 : 16 * 512];
    __shared__ float red_s[16][9];
    __shared__ float red_q[16][9];

    const int tid  = threadIdx.x;
    const int w    = tid >> 6;
    const int lane = tid & 63;
    const int lhi  = lane >> 4;
    const int llo  = lane & 15;
    const int m0   = blockIdx.x * 16;

    for (int i = tid; i < 1024; i += 512) *(short8*)&hn_s[i * 8] = short8{};
    if (!HOIST) {
#pragma unroll
        for (int rr = 0; rr < 2; ++rr) {
            const int r = w * 2 + rr;
            ln_row_pk(seq + (size_t)(m0 + r) * 512, gxw, bxw, xn_s, r, lane);
        }
    }
    __syncthreads();

    for (int t = 0; t < TT; ++t) {
        const unsigned short* gxt = HOIST ? gx + (((size_t)t * 128 + blockIdx.x) * 96) * 256 + lane * 4 : nullptr;

        // ---------- rz GEMM ----------
        {
            f32x4 aR[4], aZ[4];
            if (HOIST) {
#pragma unroll
                for (int f = 0; f < 4; ++f) {
                    short4v g1 = *(const short4v*)(gxt + (size_t)(w * 4 + f) * 256);
                    short4v g2 = *(const short4v*)(gxt + (size_t)(32 + w * 4 + f) * 256);
#pragma unroll
                    for (int i = 0; i < 4; ++i) {
                        aR[f][i] = bf2f((unsigned short)g1[i]);
                        aZ[f][i] = bf2f((unsigned short)g2[i]);
                    }
                }
#pragma unroll 4
                for (int ks = 0; ks < 16; ++ks) {
                    short8 a = *(const short8*)&hn_s[(ks * 64 + lane) * 8];
                    const int off = ks * 512 + lane * 8;
#pragma unroll
                    for (int f = 0; f < 4; ++f) {
                        short8 b1 = *(const short8*)(Wrz + (size_t)(w * 4 + f) * 8192 + off);
                        aR[f] = __builtin_amdgcn_mfma_f32_16x16x32_bf16(a, b1, aR[f], 0, 0, 0);
                        short8 b2 = *(const short8*)(Wrz + (size_t)(32 + w * 4 + f) * 8192 + off);
                        aZ[f] = __builtin_amdgcn_mfma_f32_16x16x32_bf16(a, b2, aZ[f], 0, 0, 0);
                    }
                }
            } else {
#pragma unroll
                for (int f = 0; f < 4; ++f) { aR[f] = f32x4{}; aZ[f] = f32x4{}; }
#pragma unroll 2
                for (int ks = 0; ks < 32; ++ks) {
                    short8 a = (ks < 16) ? *(const short8*)&xn_s[(ks * 64 + lane) * 8]
                                         : *(const short8*)&hn_s[((ks - 16) * 64 + lane) * 8];
                    const int off = ks * 512 + lane * 8;
#pragma unroll
                    for (int f = 0; f < 4; ++f) {
                        short8 b1 = *(const short8*)(Wrz + (size_t)(w * 4 + f) * 16384 + off);
                        aR[f] = __builtin_amdgcn_mfma_f32_16x16x32_bf16(a, b1, aR[f], 0, 0, 0);
                        short8 b2 = *(const short8*)(Wrz + (size_t)(32 + w * 4 + f) * 16384 + off);
                        aZ[f] = __builtin_amdgcn_mfma_f32_16x16x32_bf16(a, b2, aZ[f], 0, 0, 0);
                    }
                }
            }
            // epilogue: r*hn -> rh_s, z -> regs (stored into aR)
#pragma unroll
            for (int f = 0; f < 4; ++f)
#pragma unroll
                for (int i = 0; i < 4; ++i) {
                    const int row = lhi * 4 + i;
                    const int col = w * 64 + f * 16 + llo;
                    const float rr = sigmoidf_(aR[f][i] + br[col]);
                    const float hv = bf2f(hn_s[pk_idx(row, col)]);
                    rh_s[pk_idx(row, col)] = f2bf(rr * hv);
                    aR[f][i] = sigmoidf_(aZ[f][i] + bz[col]);
                }
            __syncthreads();   // bar1: rh ready

            // ---------- c GEMM ----------
            f32x4 aC[4];
            if (HOIST) {
#pragma unroll
                for (int f = 0; f < 4; ++f) {
                    short4v g3 = *(const short4v*)(gxt + (size_t)(64 + w * 4 + f) * 256);
#pragma unroll
                    for (int i = 0; i < 4; ++i) aC[f][i] = bf2f((unsigned short)g3[i]);
                }
#pragma unroll 4
                for (int ks = 0; ks < 16; ++ks) {
                    short8 a = *(const short8*)&rh_s[(ks * 64 + lane) * 8];
                    const int off = ks * 512 + lane * 8;
#pragma unroll
                    for (int f = 0; f < 4; ++f) {
                        short8 b1 = *(const short8*)(Wc + (size_t)(w * 4 + f) * 8192 + off);
                        aC[f] = __builtin_amdgcn_mfma_f32_16x16x32_bf16(a, b1, aC[f], 0, 0, 0);
                    }
                }
            } else {
#pragma unroll
                for (int f = 0; f < 4; ++f) aC[f] = f32x4{};
#pragma unroll 2
                for (int ks = 0; ks < 32; ++ks) {
                    short8 a = (ks < 16) ? *(const short8*)&xn_s[(ks * 64 + lane) * 8]
                                         : *(const short8*)&rh_s[((ks - 16) * 64 + lane) * 8];
                    const int off = ks * 512 + lane * 8;
#pragma unroll
                    for (int f = 0; f < 4; ++f) {
                        short8 b1 = *(const short8*)(Wc + (size_t)(w * 4 + f) * 16384 + off);
                        aC[f] = __builtin_amdgcn_mfma_f32_16x16x32_bf16(a, b1, aC[f], 0, 0, 0);
                    }
                }
            }
            __syncthreads();   // bar2: all LDS reads done

            // ---------- epilogue: blend, LN1 -> states, LN2*exp(-dt) -> hn ----------
            float hnew[4][4];
#pragma unroll
            for (int f = 0; f < 4; ++f)
#pragma unroll
                for (int i = 0; i < 4; ++i) {
                    const int row = lhi * 4 + i;
                    const int col = w * 64 + f * 16 + llo;
                    const float htil = tanhf_(aC[f][i] + bc[col]);
                    const float hv = bf2f(hn_s[pk_idx(row, col)]);
                    const float z = aR[f][i];
                    hnew[f][i] = (1.0f - z) * hv + z * htil;
                }
#pragma unroll
            for (int i = 0; i < 4; ++i) {
                float s = hnew[0][i] + hnew[1][i] + hnew[2][i] + hnew[3][i];
                float q = hnew[0][i]*hnew[0][i] + hnew[1][i]*hnew[1][i]
                        + hnew[2][i]*hnew[2][i] + hnew[3][i]*hnew[3][i];
#pragma unroll
                for (int m = 8; m >= 1; m >>= 1) { s += __shfl_xor(s, m); q += __shfl_xor(q, m); }
                if (llo == 0) { red_s[lhi * 4 + i][w] = s; red_q[lhi * 4 + i][w] = q; }
            }
            __syncthreads();
            float mu[4], rsd[4];
#pragma unroll
            for (int i = 0; i < 4; ++i) {
                float s = 0.f, q = 0.f;
#pragma unroll
                for (int w2 = 0; w2 < 8; ++w2) { s += red_s[lhi * 4 + i][w2]; q += red_q[lhi * 4 + i][w2]; }
                const float m_ = s * (1.0f / 512.0f);
                mu[i]  = m_;
                rsd[i] = rsqrtf(q * (1.0f / 512.0f) - m_ * m_ + 1e-5f);
            }
#pragma unroll
            for (int f = 0; f < 4; ++f)
#pragma unroll
                for (int i = 0; i < 4; ++i) {
                    const int row = lhi * 4 + i;
                    const int col = w * 64 + f * 16 + llo;
                    const float h = (hnew[f][i] - mu[i]) * rsd[i] * gc[col] + bcl[col];
                    if (SBF) states_pk[((size_t)t * 128 + blockIdx.x) * 8192 + pk_idx(row, col)] = f2bf(h);
                    else     states_f32[(size_t)t * BB * 512 + (size_t)(m0 + row) * 512 + col] = h;
                    hnew[f][i] = h;
                }
            if (t + 1 < TT) {
                __syncthreads();
#pragma unroll
                for (int i = 0; i < 4; ++i) {
                    float s = hnew[0][i] + hnew[1][i] + hnew[2][i] + hnew[3][i];
                    float q = hnew[0][i]*hnew[0][i] + hnew[1][i]*hnew[1][i]
                            + hnew[2][i]*hnew[2][i] + hnew[3][i]*hnew[3][i];
#pragma unroll
                    for (int m = 8; m >= 1; m >>= 1) { s += __shfl_xor(s, m); q += __shfl_xor(q, m); }
                    if (llo == 0) { red_s[lhi * 4 + i][w] = s; red_q[lhi * 4 + i][w] = q; }
                }
                __syncthreads();
                float dec_[4];
#pragma unroll
                for (int i = 0; i < 4; ++i) {
                    float s = 0.f, q = 0.f;
#pragma unroll
                    for (int w2 = 0; w2 < 8; ++w2) { s += red_s[lhi * 4 + i][w2]; q += red_q[lhi * 4 + i][w2]; }
                    const float m_ = s * (1.0f / 512.0f);
                    mu[i]  = m_;
                    rsd[i] = rsqrtf(q * (1.0f / 512.0f) - m_ * m_ + 1e-5f);
                    const int grow = m0 + lhi * 4 + i;
                    float dtv = ts[(size_t)grow * TT + t + 1] - ts[(size_t)grow * TT + t];
                    dtv = fminf(fmaxf(dtv, 0.0f), 10.0f);
                    dec_[i] = expf(-dtv);
                }
#pragma unroll
                for (int f = 0; f < 4; ++f)
#pragma unroll
                    for (int i = 0; i < 4; ++i) {
                        const int row = lhi * 4 + i;
                        const int col = w * 64 + f * 16 + llo;
                        const float hv = ((hnew[f][i] - mu[i]) * rsd[i] * gh[col] + bh[col]) * dec_[i];
                        hn_s[pk_idx(row, col)] = f2bf(hv);
                    }
                if (!HOIST) {
#pragma unroll
                    for (int rr = 0; rr < 2; ++rr) {
                        const int r = w * 2 + rr;
                        ln_row_pk(seq + ((size_t)(t + 1) * BB + m0 + r) * 512, gxw, bxw, xn_s, r, lane);
                    }
                }
            }
        }
        __syncthreads();
    }
}

// ---------------- final projection + residual + LN ----------------
template<int BF>
__global__ __launch_bounds__(512)
void proj_kernel(const float* __restrict__ S, const unsigned short* __restrict__ Spk,
                 const unsigned short* __restrict__ Wo, const float* __restrict__ bo,
                 const float* __restrict__ seq, const float* __restrict__ gf,
                 const float* __restrict__ bff, float* __restrict__ out)
{
    const int tid  = threadIdx.x;
    const int wave = tid >> 6;
    const int lane = tid & 63;
    const int lhi  = lane >> 4;
    const int llo  = lane & 15;
    const long m0  = (long)blockIdx.x * 64;
    const int t    = (int)(m0 >> 11);
    const int blk  = (int)((m0 & 2047) >> 4);

    f32x4 acc[4][4] = {};
#pragma unroll 2
    for (int ks = 0; ks < 16; ++ks) {
        short8 a[4], b[4];
#pragma unroll
        for (int mf = 0; mf < 4; ++mf) {
            if (BF) {
                a[mf] = *(const short8*)(Spk + ((size_t)t * 128 + blk + mf) * 8192 + (ks * 64 + lane) * 8);
            } else {
                const float* ap = S + (size_t)(m0 + mf * 16 + llo) * 512 + ks * 32 + lhi * 8;
                float4 f0 = *(const float4*)ap;
                float4 f1 = *(const float4*)(ap + 4);
                short8 av;
                av[0] = (short)f2bf(f0.x); av[1] = (short)f2bf(f0.y);
                av[2] = (short)f2bf(f0.z); av[3] = (short)f2bf(f0.w);
                av[4] = (short)f2bf(f1.x); av[5] = (short)f2bf(f1.y);
                av[6] = (short)f2bf(f1.z); av[7] = (short)f2bf(f1.w);
                a[mf] = av;
            }
        }
#pragma unroll
        for (int nf = 0; nf < 4; ++nf)
            b[nf] = *(const short8*)(Wo + (size_t)(wave * 4 + nf) * 8192 + ks * 512 + lane * 8);
#pragma unroll
        for (int mf = 0; mf < 4; ++mf)
#pragma unroll
            for (int nf = 0; nf < 4; ++nf)
                acc[mf][nf] = __builtin_amdgcn_mfma_f32_16x16x32_bf16(a[mf], b[nf], acc[mf][nf], 0, 0, 0);
    }

    __shared__ float red_s[64][9];
    __shared__ float red_q[64][9];

#pragma unroll
    for (int mf = 0; mf < 4; ++mf)
#pragma unroll
        for (int i = 0; i < 4; ++i) {
            const long row = m0 + mf * 16 + lhi * 4 + i;
#pragma unroll
            for (int nf = 0; nf < 4; ++nf) {
                const int col = wave * 64 + nf * 16 + llo;
                acc[mf][nf][i] += bo[col] + seq[(size_t)row * 512 + col];
            }
        }
    float mu[4][4], rstd[4][4];
#pragma unroll
    for (int mf = 0; mf < 4; ++mf)
#pragma unroll
        for (int i = 0; i < 4; ++i) {
            float s = 0.f, q = 0.f;
#pragma unroll
            for (int nf = 0; nf < 4; ++nf) { const float v = acc[mf][nf][i]; s += v; q += v * v; }
#pragma unroll
            for (int m = 8; m >= 1; m >>= 1) { s += __shfl_xor(s, m); q += __shfl_xor(q, m); }
            if (llo == 0) { red_s[mf * 16 + lhi * 4 + i][wave] = s; red_q[mf * 16 + lhi * 4 + i][wave] = q; }
        }
    __syncthreads();
#pragma unroll
    for (int mf = 0; mf < 4; ++mf)
#pragma unroll
        for (int i = 0; i < 4; ++i) {
            const int rl = mf * 16 + lhi * 4 + i;
            float s = 0.f, q = 0.f;
#pragma unroll
            for (int w2 = 0; w2 < 8; ++w2) { s += red_s[rl][w2]; q += red_q[rl][w2]; }
            const float m_ = s * (1.0f / 512.0f);
            mu[mf][i] = m_;
            rstd[mf][i] = rsqrtf(q * (1.0f / 512.0f) - m_ * m_ + 1e-5f);
        }
#pragma unroll
    for (int mf = 0; mf < 4; ++mf)
#pragma unroll
        for (int i = 0; i < 4; ++i) {
            const long row = m0 + mf * 16 + lhi * 4 + i;
#pragma unroll
            for (int nf = 0; nf < 4; ++nf) {
                const int col = wave * 64 + nf * 16 + llo;
                out[(size_t)row * 512 + col] = (acc[mf][nf][i] - mu[mf][i]) * rstd[mf][i] * gf[col] + bff[col];
            }
        }
}

extern "C" void kernel_launch(void* const* d_in, const int* in_sizes, int n_in,
                              void* d_out, int out_size, void* d_ws, size_t ws_size,
                              hipStream_t stream) {
    const float* seq = (const float*)d_in[0];
    const float* ts  = (const float*)d_in[1];
    const float* Wr  = (const float*)d_in[2];
    const float* br  = (const float*)d_in[3];
    const float* Wz  = (const float*)d_in[4];
    const float* bz  = (const float*)d_in[5];
    const float* Wc  = (const float*)d_in[6];
    const float* bc  = (const float*)d_in[7];
    const float* Wo  = (const float*)d_in[8];
    const float* bo  = (const float*)d_in[9];
    const float* gx  = (const float*)d_in[10];
    const float* bx  = (const float*)d_in[11];
    const float* gh  = (const float*)d_in[12];
    const float* bh  = (const float*)d_in[13];
    const float* gc  = (const float*)d_in[14];
    const float* bcl = (const float*)d_in[15];
    const float* gf  = (const float*)d_in[16];
    const float* bf  = (const float*)d_in[17];
    float* out = (float*)d_out;

    char* w0 = (char*)d_ws;
    char* w = w0;
    unsigned short* Wrz_full = (unsigned short*)w; w += (size_t)1024 * 1024 * 2;
    unsigned short* Wc_full  = (unsigned short*)w; w += (size_t)512 * 1024 * 2;
    unsigned short* Wrz_h    = (unsigned short*)w; w += (size_t)1024 * 512 * 2;
    unsigned short* Wc_h     = (unsigned short*)w; w += (size_t)512 * 512 * 2;
    unsigned short* Wx3      = (unsigned short*)w; w += (size_t)1536 * 512 * 2;
    unsigned short* Wo_pk    = (unsigned short*)w; w += (size_t)512 * 512 * 2;

    const size_t GXB = (size_t)TT * 128 * 96 * 256 * 2;      // 402,653,184
    const size_t SBB = (size_t)TT * 128 * 8192 * 2;          // 134,217,728

    const bool hoist = ws_size >= (size_t)(w - w0) + GXB;
    unsigned short* gxbuf = (unsigned short*)w;
    if (hoist) w += GXB;
    const bool sbf = ws_size >= (size_t)(w - w0) + SBB;
    unsigned short* states_pk = (unsigned short*)w;

    if (hoist) {
        pack_all<<<7168, 256, 0, stream>>>(Wr, Wz, Wc, Wo, Wrz_h, Wc_h, Wx3, Wo_pk);
    } else {
        pack_w2<<<2048, 256, 0, stream>>>(Wr, Wrz_full, 512, 1024, 0, 1024);
        pack_w2<<<2048, 256, 0, stream>>>(Wz, Wrz_full + (size_t)512 * 1024, 512, 1024, 0, 1024);
        pack_w2<<<2048, 256, 0, stream>>>(Wc, Wc_full, 512, 1024, 0, 1024);
        pack_w2<<<1024, 256, 0, stream>>>(Wo, Wo_pk, 512, 512, 0, 512);
    }

    if (hoist)
        gx_kernel<<<2048, 512, 0, stream>>>(seq, gx, bx, Wx3, gxbuf);

    const unsigned short* Wa = hoist ? Wrz_h : Wrz_full;
    const unsigned short* Wb = hoist ? Wc_h  : Wc_full;
    if (hoist) {
        if (sbf) recurrent_kernel<1,1><<<128, 512, 0, stream>>>(seq, ts, Wa, Wb, br, bz, bc, gx, bx, gh, bh, gc, bcl, gxbuf, out, states_pk);
        else     recurrent_kernel<0,1><<<128, 512, 0, stream>>>(seq, ts, Wa, Wb, br, bz, bc, gx, bx, gh, bh, gc, bcl, gxbuf, out, states_pk);
    } else {
        if (sbf) recurrent_kernel<1,0><<<128, 512, 0, stream>>>(seq, ts, Wa, Wb, br, bz, bc, gx, bx, gh, bh, gc, bcl, gxbuf, out, states_pk);
        else     recurrent_kernel<0,0><<<128, 512, 0, stream>>>(seq, ts, Wa, Wb, br, bz, bc, gx, bx, gh, bh, gc, bcl, gxbuf, out, states_pk);
    }

    if (sbf)
        proj_kernel<1><<<2048, 512, 0, stream>>>(nullptr, states_pk, Wo_pk, bo, seq, gf, bf, out);
    else
        proj_kernel<0><<<2048, 512, 0, stream>>>(out, nullptr, Wo_pk, bo, seq, gf, bf, out);
}